// Round 10
// baseline (238.611 us; speedup 1.0000x reference)
//
#include <hip/hip_runtime.h>

// SpriteAssembler via MFMA, operand-swapped, identity-folded:
//   ACC[64i][16px] = W'[64i][64k] x B[64k][16px]   (f16 in, f32 acc)
// W part:   W[i][j] = tanh(relu(d_j - d_i)),  B[j][px] = log2(1 - s[px][j])
// id part:  acc[it] += Id x log2(s)  -- one extra MFMA per 16-row i-tile.
// masks = exp2(ACC) row-normalized (+eps).
// R10: R6 body byte-for-byte, but the tile loop is FORCED ROLLED
//     (#pragma clang loop unroll(disable)) so all resident waves execute a
//     single ~2KB hot loop instead of 10-20KB of straight-line code.
//     Tests the instruction-fetch/L1I theory of the invariant ~82us floor.
//     Prefetch address is branchlessly clamped so the body stays one block.

typedef __attribute__((ext_vector_type(8))) _Float16 half8;
typedef __attribute__((ext_vector_type(4))) float floatx4;

#define EPSF 1e-6f

__device__ inline float fast_exp2(float x){ return __builtin_amdgcn_exp2f(x); }
__device__ inline float fast_log2(float x){ return __builtin_amdgcn_logf(x); }  // log2
__device__ inline float fast_rcp (float x){ return __builtin_amdgcn_rcpf(x); }

__global__ __launch_bounds__(256, 2) void sprite_mfma_kernel(
    const float* __restrict__ shapes,   // [8, 65536, 64]
    const float* __restrict__ depths,   // [8, 64]
    float* __restrict__ out)            // [8, 65536, 64]
{
    const int wave  = threadIdx.x >> 6;
    const int lane  = threadIdx.x & 63;
    const int batch = blockIdx.x >> 7;   // 128 blocks per batch
    const int rblk  = blockIdx.x & 127;
    const int wid   = rblk * 4 + wave;   // wave id within batch [0,512), 128 px each

    __shared__ float dsh[64];
    __shared__ __align__(16) float ustage[4][16][68];  // per-wave u-tile, +4 pad

    if (threadIdx.x < 64) dsh[threadIdx.x] = depths[batch * 64 + threadIdx.x];
    __syncthreads();

    const int c = lane & 15;   // A: m(i-local). B: n(px). D: col(px)
    const int q = lane >> 4;   // k-quad / D row group

    // ---- W fragments (A-operand), built once per wave, amortized over 128 px ----
    half8 Aw[4][2];
    #pragma unroll
    for (int it = 0; it < 4; ++it) {
        float di = dsh[it * 16 + c];
        #pragma unroll
        for (int kt = 0; kt < 2; ++kt) {
            half8 h;
            #pragma unroll
            for (int jj = 0; jj < 8; ++jj) {
                int j = kt * 32 + q * 8 + jj;
                float x = fmaxf(dsh[j] - di, 0.0f);            // relu(d_j - d_i)
                float e = fast_exp2(x * 2.885390082f);         // e^{2x}
                h[jj] = (_Float16)((e - 1.0f) * fast_rcp(e + 1.0f));  // tanh
            }
            Aw[it][kt] = h;
        }
    }

    // identity A-fragments: nonzero only where k_local == (it&1)*16 + m
    half8 idlo, idhi;
    #pragma unroll
    for (int jj = 0; jj < 8; ++jj) {
        idlo[jj] = (q * 8 + jj == c)      ? (_Float16)1.0f : (_Float16)0.0f;
        idhi[jj] = (q * 8 + jj == 16 + c) ? (_Float16)1.0f : (_Float16)0.0f;
    }

    const long pxbase = (long)batch * 65536 + (long)wid * 128;
    const float* sp = shapes + (pxbase + c) * 64 + q * 8;  // lane's row chunk, tile 0
    float* const obase0 = out + pxbase * 64;               // wave's contiguous 32KB

    // B-layout loads: lane reads s[px=c][q*8 .. q*8+7] and the +32 block.
    float4 pf0 = *(const float4*)(sp);
    float4 pf1 = *(const float4*)(sp + 4);
    float4 pf2 = *(const float4*)(sp + 32);
    float4 pf3 = *(const float4*)(sp + 36);

    // ---- ROLLED tile loop: one shared ~2KB hot body for all waves ----
    #pragma clang loop unroll(disable)
    for (int tile = 0; tile < 8; ++tile) {
        float4 s0 = pf0, s1 = pf1, s2 = pf2, s3 = pf3;
        {   // branchless prefetch: tile 7 re-reads its own (L1-hot) chunk
            int tn = tile < 7 ? tile + 1 : 7;
            const float* sn = sp + tn * 16 * 64;
            pf0 = *(const float4*)(sn);
            pf1 = *(const float4*)(sn + 4);
            pf2 = *(const float4*)(sn + 32);
            pf3 = *(const float4*)(sn + 36);
        }

        float sv[16] = {s0.x, s0.y, s0.z, s0.w, s1.x, s1.y, s1.z, s1.w,
                        s2.x, s2.y, s2.z, s2.w, s3.x, s3.y, s3.z, s3.w};
        half8 B_lo, B_hi;                        // B[j][px=c]  = log2(1 - s)
        half8 C_lo, C_hi;                        // B2[j][px=c] = log2(s)
        #pragma unroll
        for (int e = 0; e < 8; ++e) {
            float slo = fminf(fmaxf(sv[e],     EPSF), 1.0f - EPSF);
            float shi = fminf(fmaxf(sv[8 + e], EPSF), 1.0f - EPSF);
            B_lo[e] = (_Float16)fast_log2(1.0f - slo);
            B_hi[e] = (_Float16)fast_log2(1.0f - shi);
            C_lo[e] = (_Float16)fast_log2(slo);
            C_hi[e] = (_Float16)fast_log2(shi);
        }

        floatx4 acc[4];
        #pragma unroll
        for (int it = 0; it < 4; ++it) {
            floatx4 a = {0.f, 0.f, 0.f, 0.f};
            a = __builtin_amdgcn_mfma_f32_16x16x32_f16(Aw[it][0], B_lo, a, 0, 0, 0);
            a = __builtin_amdgcn_mfma_f32_16x16x32_f16(Aw[it][1], B_hi, a, 0, 0, 0);
            a = __builtin_amdgcn_mfma_f32_16x16x32_f16(
                    (it & 1) ? idhi : idlo, (it < 2) ? C_lo : C_hi, a, 0, 0, 0);
            acc[it] = a;
        }

        // D layout: value (it, r) is ACC[i = it*16 + q*4 + r][px = tile*16 + c]
        float u[4][4];
        float tot = 0.f;
        #pragma unroll
        for (int it = 0; it < 4; ++it) {
            #pragma unroll
            for (int r = 0; r < 4; ++r) {
                float v = fast_exp2(acc[it][r]);
                u[it][r] = v;
                tot += v;
            }
        }
        tot += __shfl_xor(tot, 16, 64);          // reduce over q-groups (all 64 i)
        tot += __shfl_xor(tot, 32, 64);
        float inv = fast_rcp(tot + EPSF);

        // ---- LDS transpose epilogue (per-wave private; no barriers) ----
        // write D-layout: row px=c, i-cols it*16+q*4 .. +4
        #pragma unroll
        for (int it = 0; it < 4; ++it) {
            floatx4 o = {u[it][0] * inv, u[it][1] * inv,
                         u[it][2] * inv, u[it][3] * inv};
            *(floatx4*)&ustage[wave][c][it * 16 + q * 4] = o;
        }
        // read store-linear: instr k covers global bytes [k*1024 + lane*16)
        // px = k*4 + q, i-cols c*4 .. +4. Tile output is contiguous 4KB.
        float* ob = obase0 + (long)tile * 16 * 64;
        #pragma unroll
        for (int k = 0; k < 4; ++k) {
            floatx4 o = *(const floatx4*)&ustage[wave][k * 4 + q][c * 4];
            *(floatx4*)(ob + k * 256 + lane * 4) = o;
        }
    }
}

extern "C" void kernel_launch(void* const* d_in, const int* in_sizes, int n_in,
                              void* d_out, int out_size, void* d_ws, size_t ws_size,
                              hipStream_t stream) {
    const float* shapes = (const float*)d_in[0];
    const float* depths = (const float*)d_in[1];
    float* out = (float*)d_out;
    // 8 batches * 128 blocks, 256 threads (4 waves), 128 px per wave
    sprite_mfma_kernel<<<1024, 256, 0, stream>>>(shapes, depths, out);
}

// Round 11
// 232.971 us; speedup vs baseline: 1.0242x; 1.0242x over previous
//
#include <hip/hip_runtime.h>

// SpriteAssembler via MFMA — R11 "microwave" decomposition.
// Theory: vmcnt is in-order, so any per-tile loop that waits on prefetch
// loads transitively waits on the PREVIOUS tile's stores retiring (L2 ack),
// serializing each wave at ~1 store round-trip per tile. Fix: no loop.
//   Kernel 1 (w_prep): W[b][i][j] = tanh(relu(d_j - d_i)) -> f16 in d_ws.
//   Kernel 2: each wave owns 16 px: load W-frags (L2) + s, one wait,
//   12 MFMA (identity-folded log2 s), exp2, shfl-reduce, LDS transpose,
//   4 x 1KB lane-contiguous stores, endpgm. Stores never block anything.

typedef __attribute__((ext_vector_type(8))) _Float16 half8;
typedef __attribute__((ext_vector_type(4))) float floatx4;

#define EPSF 1e-6f

__device__ inline float fast_exp2(float x){ return __builtin_amdgcn_exp2f(x); }
__device__ inline float fast_log2(float x){ return __builtin_amdgcn_logf(x); }  // log2
__device__ inline float fast_rcp (float x){ return __builtin_amdgcn_rcpf(x); }

__global__ __launch_bounds__(64) void w_prep_kernel(
    const float* __restrict__ depths,   // [8, 64]
    _Float16* __restrict__ w)           // [8, 64, 64]
{
    const int b = blockIdx.x;
    const int i = threadIdx.x;
    __shared__ float dsh[64];
    dsh[i] = depths[b * 64 + i];
    __syncthreads();
    const float di = dsh[i];
    _Float16* wrow = w + (b * 64 + i) * 64;
    #pragma unroll
    for (int kt = 0; kt < 8; ++kt) {
        half8 h;
        #pragma unroll
        for (int jj = 0; jj < 8; ++jj) {
            float x = fmaxf(dsh[kt * 8 + jj] - di, 0.0f);      // relu(d_j - d_i)
            float e = fast_exp2(x * 2.885390082f);             // e^{2x}
            h[jj] = (_Float16)((e - 1.0f) * fast_rcp(e + 1.0f));  // tanh
        }
        *(half8*)(wrow + kt * 8) = h;
    }
}

__global__ __launch_bounds__(256, 2) void sprite_mfma_kernel(
    const float* __restrict__ shapes,   // [8, 65536, 64]
    const _Float16* __restrict__ w,     // [8, 64, 64] precomputed
    float* __restrict__ out)            // [8, 65536, 64]
{
    const int wave  = threadIdx.x >> 6;
    const int lane  = threadIdx.x & 63;
    const int batch = blockIdx.x >> 10;  // 1024 blocks per batch
    const int rblk  = blockIdx.x & 1023;
    const int wid   = rblk * 4 + wave;   // wave id within batch [0,4096), 16 px

    __shared__ __align__(16) float ustage[4][16][68];  // per-wave u-tile, +4 pad

    const int c = lane & 15;   // A: m(i-local). B: n(px). D: col(px)
    const int q = lane >> 4;   // k-quad / D row group

    // ---- W fragments: 8 x 16B loads, L2-resident (64KB total, shared) ----
    // Aw[it][kt][jj] = w[i = it*16+c][j = kt*32 + q*8 + jj]
    half8 Aw[4][2];
    const _Float16* wb = w + batch * 4096;
    #pragma unroll
    for (int it = 0; it < 4; ++it) {
        #pragma unroll
        for (int kt = 0; kt < 2; ++kt)
            Aw[it][kt] = *(const half8*)(wb + (it * 16 + c) * 64 + kt * 32 + q * 8);
    }

    // identity A-fragments: nonzero only where k_local == (it&1)*16 + m
    half8 idlo, idhi;
    #pragma unroll
    for (int jj = 0; jj < 8; ++jj) {
        idlo[jj] = (q * 8 + jj == c)      ? (_Float16)1.0f : (_Float16)0.0f;
        idhi[jj] = (q * 8 + jj == 16 + c) ? (_Float16)1.0f : (_Float16)0.0f;
    }

    // ---- s loads: lane reads s[px=c][q*8 .. +8] and the +32 block ----
    const long px0 = (long)batch * 65536 + (long)wid * 16;
    const float* sp = shapes + (px0 + c) * 64 + q * 8;
    float4 s0 = *(const float4*)(sp);
    float4 s1 = *(const float4*)(sp + 4);
    float4 s2 = *(const float4*)(sp + 32);
    float4 s3 = *(const float4*)(sp + 36);

    float sv[16] = {s0.x, s0.y, s0.z, s0.w, s1.x, s1.y, s1.z, s1.w,
                    s2.x, s2.y, s2.z, s2.w, s3.x, s3.y, s3.z, s3.w};
    half8 B_lo, B_hi;                        // B[j][px=c]  = log2(1 - s)
    half8 C_lo, C_hi;                        // B2[j][px=c] = log2(s)
    #pragma unroll
    for (int e = 0; e < 8; ++e) {
        float slo = fminf(fmaxf(sv[e],     EPSF), 1.0f - EPSF);
        float shi = fminf(fmaxf(sv[8 + e], EPSF), 1.0f - EPSF);
        B_lo[e] = (_Float16)fast_log2(1.0f - slo);
        B_hi[e] = (_Float16)fast_log2(1.0f - shi);
        C_lo[e] = (_Float16)fast_log2(slo);
        C_hi[e] = (_Float16)fast_log2(shi);
    }

    floatx4 acc[4];
    #pragma unroll
    for (int it = 0; it < 4; ++it) {
        floatx4 a = {0.f, 0.f, 0.f, 0.f};
        a = __builtin_amdgcn_mfma_f32_16x16x32_f16(Aw[it][0], B_lo, a, 0, 0, 0);
        a = __builtin_amdgcn_mfma_f32_16x16x32_f16(Aw[it][1], B_hi, a, 0, 0, 0);
        a = __builtin_amdgcn_mfma_f32_16x16x32_f16(
                (it & 1) ? idhi : idlo, (it < 2) ? C_lo : C_hi, a, 0, 0, 0);
        acc[it] = a;
    }

    // D layout: value (it, r) is ACC[i = it*16 + q*4 + r][px = c]
    float u[4][4];
    float tot = 0.f;
    #pragma unroll
    for (int it = 0; it < 4; ++it) {
        #pragma unroll
        for (int r = 0; r < 4; ++r) {
            float v = fast_exp2(acc[it][r]);
            u[it][r] = v;
            tot += v;
        }
    }
    tot += __shfl_xor(tot, 16, 64);          // reduce over q-groups (all 64 i)
    tot += __shfl_xor(tot, 32, 64);
    float inv = fast_rcp(tot + EPSF);

    // ---- LDS transpose epilogue (per-wave private; no barriers) ----
    #pragma unroll
    for (int it = 0; it < 4; ++it) {
        floatx4 o = {u[it][0] * inv, u[it][1] * inv,
                     u[it][2] * inv, u[it][3] * inv};
        *(floatx4*)&ustage[wave][c][it * 16 + q * 4] = o;
    }
    // store-linear: instr k covers global bytes [k*1024 + lane*16)
    float* ob = out + px0 * 64;
    #pragma unroll
    for (int k = 0; k < 4; ++k) {
        floatx4 o = *(const floatx4*)&ustage[wave][k * 4 + q][c * 4];
        *(floatx4*)(ob + k * 256 + lane * 4) = o;  // fire-and-forget
    }
}

extern "C" void kernel_launch(void* const* d_in, const int* in_sizes, int n_in,
                              void* d_out, int out_size, void* d_ws, size_t ws_size,
                              hipStream_t stream) {
    const float* shapes = (const float*)d_in[0];
    const float* depths = (const float*)d_in[1];
    float* out = (float*)d_out;
    _Float16* w = (_Float16*)d_ws;           // 8*64*64*2B = 64 KB
    w_prep_kernel<<<8, 64, 0, stream>>>(depths, w);
    // 8 batches * 1024 blocks, 256 threads (4 waves), 16 px per wave
    sprite_mfma_kernel<<<8192, 256, 0, stream>>>(shapes, w, out);
}

// Round 13
// 230.710 us; speedup vs baseline: 1.0342x; 1.0098x over previous
//
#include <hip/hip_runtime.h>

// SpriteAssembler via MFMA — R12 (resubmit; prior run died to a container
// failure, not a kernel error): microwave decomposition, 2 microtiles/wave.
// R11 proved the floor was vmcnt in-order store coupling: per-tile loops wait
// on loads AFTER stores -> every tile pays a store round-trip. R11 (no loop,
// 16px/wave) dropped below the 79us fill dispatches. R12 amortizes per-wave
// overhead (8 W-frag L2 loads, id-frag build, addressing) over 32 px while
// KEEPING decoupling: ALL s-loads are issued before ANY store, so the wait
// for tile1's s-data is on ops older than tile0's stores (in-order vmcnt
// never requires store retirement). Stores remain fire-and-forget.
//   Kernel 1 (w_prep): W[b][i][j] = tanh(relu(d_j - d_i)) -> f16 in d_ws.
//   Kernel 2: per wave: 8 W loads + 8 s loads -> tile0 compute/store,
//   tile1 compute/store, endpgm. LDS transpose double-buffered.

typedef __attribute__((ext_vector_type(8))) _Float16 half8;
typedef __attribute__((ext_vector_type(4))) float floatx4;

#define EPSF 1e-6f

__device__ inline float fast_exp2(float x){ return __builtin_amdgcn_exp2f(x); }
__device__ inline float fast_log2(float x){ return __builtin_amdgcn_logf(x); }  // log2
__device__ inline float fast_rcp (float x){ return __builtin_amdgcn_rcpf(x); }

__global__ __launch_bounds__(64) void w_prep_kernel(
    const float* __restrict__ depths,   // [8, 64]
    _Float16* __restrict__ w)           // [8, 64, 64]
{
    const int b = blockIdx.x;
    const int i = threadIdx.x;
    __shared__ float dsh[64];
    dsh[i] = depths[b * 64 + i];
    __syncthreads();
    const float di = dsh[i];
    _Float16* wrow = w + (b * 64 + i) * 64;
    #pragma unroll
    for (int kt = 0; kt < 8; ++kt) {
        half8 h;
        #pragma unroll
        for (int jj = 0; jj < 8; ++jj) {
            float x = fmaxf(dsh[kt * 8 + jj] - di, 0.0f);      // relu(d_j - d_i)
            float e = fast_exp2(x * 2.885390082f);             // e^{2x}
            h[jj] = (_Float16)((e - 1.0f) * fast_rcp(e + 1.0f));  // tanh
        }
        *(half8*)(wrow + kt * 8) = h;
    }
}

__global__ __launch_bounds__(256, 3) void sprite_mfma_kernel(
    const float* __restrict__ shapes,   // [8, 65536, 64]
    const _Float16* __restrict__ w,     // [8, 64, 64] precomputed
    float* __restrict__ out)            // [8, 65536, 64]
{
    const int wave  = threadIdx.x >> 6;
    const int lane  = threadIdx.x & 63;
    const int batch = blockIdx.x >> 9;   // 512 blocks per batch
    const int rblk  = blockIdx.x & 511;
    const int wid   = rblk * 4 + wave;   // wave id within batch [0,2048), 32 px

    __shared__ __align__(16) float ustage[4][2][16][68];  // [wave][buf][px][i]+pad

    const int c = lane & 15;   // A: m(i-local). B: n(px). D: col(px)
    const int q = lane >> 4;   // k-quad / D row group

    // ---- W fragments: 8 x 16B loads, L2-resident, amortized over 32 px ----
    half8 Aw[4][2];
    const _Float16* wb = w + batch * 4096;
    #pragma unroll
    for (int it = 0; it < 4; ++it) {
        #pragma unroll
        for (int kt = 0; kt < 2; ++kt)
            Aw[it][kt] = *(const half8*)(wb + (it * 16 + c) * 64 + kt * 32 + q * 8);
    }

    // identity A-fragments: nonzero only where k_local == (it&1)*16 + m
    half8 idlo, idhi;
    #pragma unroll
    for (int jj = 0; jj < 8; ++jj) {
        idlo[jj] = (q * 8 + jj == c)      ? (_Float16)1.0f : (_Float16)0.0f;
        idhi[jj] = (q * 8 + jj == 16 + c) ? (_Float16)1.0f : (_Float16)0.0f;
    }

    // ---- ALL s-loads up-front (before any store): tiles 0 and 1 ----
    const long px0 = (long)batch * 65536 + (long)wid * 32;
    const float* sp = shapes + (px0 + c) * 64 + q * 8;       // tile0
    float4 a0 = *(const float4*)(sp);
    float4 a1 = *(const float4*)(sp + 4);
    float4 a2 = *(const float4*)(sp + 32);
    float4 a3 = *(const float4*)(sp + 36);
    const float* sq = sp + 16 * 64;                          // tile1
    float4 b0 = *(const float4*)(sq);
    float4 b1 = *(const float4*)(sq + 4);
    float4 b2 = *(const float4*)(sq + 32);
    float4 b3 = *(const float4*)(sq + 36);

    auto process = [&](float4 s0, float4 s1, float4 s2, float4 s3,
                       int t, int buf) {
        float sv[16] = {s0.x, s0.y, s0.z, s0.w, s1.x, s1.y, s1.z, s1.w,
                        s2.x, s2.y, s2.z, s2.w, s3.x, s3.y, s3.z, s3.w};
        half8 B_lo, B_hi;                    // B[j][px=c]  = log2(1 - s)
        half8 C_lo, C_hi;                    // B2[j][px=c] = log2(s)
        #pragma unroll
        for (int e = 0; e < 8; ++e) {
            float slo = fminf(fmaxf(sv[e],     EPSF), 1.0f - EPSF);
            float shi = fminf(fmaxf(sv[8 + e], EPSF), 1.0f - EPSF);
            B_lo[e] = (_Float16)fast_log2(1.0f - slo);
            B_hi[e] = (_Float16)fast_log2(1.0f - shi);
            C_lo[e] = (_Float16)fast_log2(slo);
            C_hi[e] = (_Float16)fast_log2(shi);
        }

        floatx4 acc[4];
        #pragma unroll
        for (int it = 0; it < 4; ++it) {
            floatx4 a = {0.f, 0.f, 0.f, 0.f};
            a = __builtin_amdgcn_mfma_f32_16x16x32_f16(Aw[it][0], B_lo, a, 0, 0, 0);
            a = __builtin_amdgcn_mfma_f32_16x16x32_f16(Aw[it][1], B_hi, a, 0, 0, 0);
            a = __builtin_amdgcn_mfma_f32_16x16x32_f16(
                    (it & 1) ? idhi : idlo, (it < 2) ? C_lo : C_hi, a, 0, 0, 0);
            acc[it] = a;
        }

        // D layout: value (it, r) is ACC[i = it*16 + q*4 + r][px = t*16 + c]
        float u[4][4];
        float tot = 0.f;
        #pragma unroll
        for (int it = 0; it < 4; ++it) {
            #pragma unroll
            for (int r = 0; r < 4; ++r) {
                float v = fast_exp2(acc[it][r]);
                u[it][r] = v;
                tot += v;
            }
        }
        tot += __shfl_xor(tot, 16, 64);      // reduce over q-groups (all 64 i)
        tot += __shfl_xor(tot, 32, 64);
        float inv = fast_rcp(tot + EPSF);

        // ---- LDS transpose epilogue (per-wave private; no barriers) ----
        #pragma unroll
        for (int it = 0; it < 4; ++it) {
            floatx4 o = {u[it][0] * inv, u[it][1] * inv,
                         u[it][2] * inv, u[it][3] * inv};
            *(floatx4*)&ustage[wave][buf][c][it * 16 + q * 4] = o;
        }
        // store-linear: instr k covers global bytes [k*1024 + lane*16)
        float* ob = out + (px0 + t * 16) * 64;
        #pragma unroll
        for (int k = 0; k < 4; ++k) {
            floatx4 o = *(const floatx4*)&ustage[wave][buf][k * 4 + q][c * 4];
            *(floatx4*)(ob + k * 256 + lane * 4) = o;  // fire-and-forget
        }
    };

    process(a0, a1, a2, a3, 0, 0);
    process(b0, b1, b2, b3, 1, 1);
}

extern "C" void kernel_launch(void* const* d_in, const int* in_sizes, int n_in,
                              void* d_out, int out_size, void* d_ws, size_t ws_size,
                              hipStream_t stream) {
    const float* shapes = (const float*)d_in[0];
    const float* depths = (const float*)d_in[1];
    float* out = (float*)d_out;
    _Float16* w = (_Float16*)d_ws;           // 8*64*64*2B = 64 KB (ws is larger)
    w_prep_kernel<<<8, 64, 0, stream>>>(depths, w);
    // 8 batches * 512 blocks, 256 threads (4 waves), 32 px per wave
    sprite_mfma_kernel<<<4096, 256, 0, stream>>>(shapes, w, out);
}